// Round 11
// baseline (150.534 us; speedup 1.0000x reference)
//
#include <hip/hip_runtime.h>

// EntityLinker forward, MI355X/gfx950. One block per batch b, 256 thr (4 waves).
// R10 = R9 structure minus the embed bf16-table pass: gather reads f32 embed
// directly (51MB table is L3-resident; gather is latency-bound, not BW-bound,
// so the ~13us conversion kernel was pure overhead). P1 deep-pipelined:
// q loads upfront, c-columns with 16 loads in flight, unroll 2.
// P2-P6 identical to R9 (proven 49.9us structure).

typedef __attribute__((ext_vector_type(8))) short     short8;
typedef __attribute__((ext_vector_type(8))) __bf16    bf16x8;
typedef __attribute__((ext_vector_type(4))) float     f32x4;
typedef __attribute__((ext_vector_type(4))) int       int4v;

#define SWZ8(row, off) ((off) ^ (((row) & 7) << 4))
#define SWZQ(row, off) ((off) ^ (((row) & 7) << 4) ^ ((((row) >> 3) & 3) << 5))

// ---- LDS layout (bytes), total 40960 ----
#define CH_OFF  0        // c_h [64][128] bf16, 256B rows, SWZ8
#define QH_OFF  16384    // q_h [64][128] bf16, 256B rows, SWZQ -> wq after P4
#define X_OFF   32768    // P1-P2: qsum partials [16][128] f32 (8KB)
                         // P3-P4: att [64][64] bf16 SWZ8 ; P5-P6: outp [4][64] f32
#define LDS_SIZE 40960

__device__ __forceinline__ unsigned short f2bf(float x) {
    __bf16 h = (__bf16)x;
    return __builtin_bit_cast(unsigned short, h);
}
__device__ __forceinline__ float bf2f(unsigned short u) {
    return __builtin_bit_cast(float, ((unsigned)u) << 16);
}
__device__ __forceinline__ unsigned pk2(float a, float b) {
    return (unsigned)f2bf(a) | ((unsigned)f2bf(b) << 16);
}
__device__ __forceinline__ f32x4 mfma16(short8 a, short8 b, f32x4 c) {
    return __builtin_amdgcn_mfma_f32_16x16x32_bf16(
        __builtin_bit_cast(bf16x8, a), __builtin_bit_cast(bf16x8, b), c, 0, 0, 0);
}

// W_h [640][128] f32 -> whT [128][640] bf16.
__global__ __launch_bounds__(256) void el_prep(const float* __restrict__ W_h,
                                               unsigned short* __restrict__ whT) {
    int t = blockIdx.x * 256 + threadIdx.x;
    int k = t >> 7, n = t & 127;
    whT[n * 640 + k] = f2bf(W_h[t]);
}

__global__ __launch_bounds__(256, 3) void el_main(
    const int* __restrict__ q_ids, const int* __restrict__ c_ids,
    const int* __restrict__ num_qs, const float* __restrict__ emb,
    const unsigned short* __restrict__ whT,
    unsigned short* __restrict__ qsum_ws,
    const float* __restrict__ b_h,
    const float* __restrict__ W_o, const float* __restrict__ b_o,
    float* __restrict__ out)
{
    __shared__ __align__(16) char smem[LDS_SIZE];
    const int tid = threadIdx.x;
    const int b = blockIdx.x;
    const int nq = num_qs[b] > 0 ? num_qs[b] : 1;

    // ---------------- P1: deep-pipelined f32 gathers ----------------
    {
        const int l4 = tid & 15, gg = tid >> 4;       // 16 groups of 16 lanes
        // 1) all ids upfront
        int4v ci[4][2];
        #pragma unroll
        for (int cc = 0; cc < 4; ++cc) {
            const int* idp = c_ids + (((b << 6) + gg + cc * 16) << 3);
            ci[cc][0] = *(const int4v*)idp;
            ci[cc][1] = *(const int4v*)(idp + 4);
        }
        int qid[4];
        #pragma unroll
        for (int qq = 0; qq < 4; ++qq)
            qid[qq] = q_ids[(b << 6) + gg + (qq << 4)];

        // 2) q row loads issued first (consumed last)
        f32x4 qlo[4], qhi[4];
        #pragma unroll
        for (int qq = 0; qq < 4; ++qq) {
            const float* p = emb + (long)qid[qq] * 128 + l4 * 8;
            qlo[qq] = *(const f32x4*)p;
            qhi[qq] = *(const f32x4*)(p + 4);
        }

        // 3) c columns: 16 loads in flight each, unroll 2 overlaps pairs
        #pragma unroll 2
        for (int cc = 0; cc < 4; ++cc) {
            const int c = gg + cc * 16;
            int id8[8] = {ci[cc][0][0], ci[cc][0][1], ci[cc][0][2], ci[cc][0][3],
                          ci[cc][1][0], ci[cc][1][1], ci[cc][1][2], ci[cc][1][3]};
            f32x4 vlo[8], vhi[8];
            #pragma unroll
            for (int t = 0; t < 8; ++t) {
                const float* p = emb + (long)id8[t] * 128 + l4 * 8;
                vlo[t] = *(const f32x4*)p;
                vhi[t] = *(const f32x4*)(p + 4);
            }
            int cnt = 0;
            #pragma unroll
            for (int t = 0; t < 8; ++t) cnt += (id8[t] != 0);
            f32x4 alo = {0.f,0.f,0.f,0.f}, ahi = {0.f,0.f,0.f,0.f};
            #pragma unroll
            for (int t = 0; t < 8; ++t) { alo += vlo[t]; ahi += vhi[t]; }
            float inv = 1.0f / (float)(cnt > 0 ? cnt : 1);
            uint4 pk;
            pk.x = pk2(alo[0]*inv, alo[1]*inv); pk.y = pk2(alo[2]*inv, alo[3]*inv);
            pk.z = pk2(ahi[0]*inv, ahi[1]*inv); pk.w = pk2(ahi[2]*inv, ahi[3]*inv);
            *(uint4*)(smem + CH_OFF + SWZ8(c, c * 256 + l4 * 16)) = pk;
        }

        // 4) q rows: pack+store + masked partial sums
        float qa[8] = {0.f,0.f,0.f,0.f,0.f,0.f,0.f,0.f};
        #pragma unroll
        for (int qq = 0; qq < 4; ++qq) {
            const int q = gg + (qq << 4);
            uint4 v;
            v.x = pk2(qlo[qq][0], qlo[qq][1]); v.y = pk2(qlo[qq][2], qlo[qq][3]);
            v.z = pk2(qhi[qq][0], qhi[qq][1]); v.w = pk2(qhi[qq][2], qhi[qq][3]);
            *(uint4*)(smem + QH_OFF + SWZQ(q, q * 256 + l4 * 16)) = v;
            if (q < nq) {
                qa[0] += qlo[qq][0]; qa[1] += qlo[qq][1];
                qa[2] += qlo[qq][2]; qa[3] += qlo[qq][3];
                qa[4] += qhi[qq][0]; qa[5] += qhi[qq][1];
                qa[6] += qhi[qq][2]; qa[7] += qhi[qq][3];
            }
        }
        float* qsp = (float*)(smem + X_OFF);
        *(f32x4*)(qsp + gg * 128 + l4 * 8)     = (f32x4){qa[0], qa[1], qa[2], qa[3]};
        *(f32x4*)(qsp + gg * 128 + l4 * 8 + 4) = (f32x4){qa[4], qa[5], qa[6], qa[7]};
    }
    __syncthreads();

    // ---------------- P2: q_summary -> global ws (bf16) ----------------
    if (tid < 128) {
        const float* qsp = (const float*)(smem + X_OFF);
        float s = 0.f;
        #pragma unroll
        for (int g = 0; g < 16; ++g) s += qsp[g * 128 + tid];
        qsum_ws[(b << 7) + tid] = f2bf(s / (float)nq);
    }
    __syncthreads();

    const int lane = tid & 63, w = tid >> 6;
    const int lr = lane & 15, lg = lane >> 4;

    // ---------------- P3: sim + in-reg softmax -> att in X ----------------
    {
        short8 a[4];
        const int arow = w * 16 + lr;
        #pragma unroll
        for (int s = 0; s < 4; ++s)
            a[s] = *(const short8*)(smem + CH_OFF + SWZ8(arow, arow * 256 + s * 64 + lg * 16));
        f32x4 sim[4];
        #pragma unroll
        for (int ct = 0; ct < 4; ++ct) {
            f32x4 acc = {0.f, 0.f, 0.f, 0.f};
            const int q = ct * 16 + lr;
            #pragma unroll
            for (int s = 0; s < 4; ++s) {
                short8 bf = *(const short8*)(smem + QH_OFF + SWZQ(q, q * 256 + s * 64 + lg * 16));
                acc = mfma16(a[s], bf, acc);
            }
            sim[ct] = acc;
        }
        const float scale = 0.08838834764831845f;  // 1/sqrt(128)
        #pragma unroll
        for (int ct = 0; ct < 4; ++ct) {
            const int q = ct * 16 + lr;
            #pragma unroll
            for (int r = 0; r < 4; ++r)
                sim[ct][r] = (q < nq) ? sim[ct][r] * scale : -3.0e38f;
        }
        float mx[4], sm[4];
        #pragma unroll
        for (int r = 0; r < 4; ++r)
            mx[r] = fmaxf(fmaxf(sim[0][r], sim[1][r]), fmaxf(sim[2][r], sim[3][r]));
        #pragma unroll
        for (int off = 1; off <= 8; off <<= 1)
            #pragma unroll
            for (int r = 0; r < 4; ++r)
                mx[r] = fmaxf(mx[r], __shfl_xor(mx[r], off));
        #pragma unroll
        for (int ct = 0; ct < 4; ++ct)
            #pragma unroll
            for (int r = 0; r < 4; ++r)
                sim[ct][r] = __expf(sim[ct][r] - mx[r]);
        #pragma unroll
        for (int r = 0; r < 4; ++r)
            sm[r] = (sim[0][r] + sim[1][r]) + (sim[2][r] + sim[3][r]);
        #pragma unroll
        for (int off = 1; off <= 8; off <<= 1)
            #pragma unroll
            for (int r = 0; r < 4; ++r)
                sm[r] += __shfl_xor(sm[r], off);
        const int cbase = w * 16 + lg * 4;
        #pragma unroll
        for (int ct = 0; ct < 4; ++ct)
            #pragma unroll
            for (int r = 0; r < 4; ++r) {
                int c = cbase + r, q = ct * 16 + lr;
                *(unsigned short*)(smem + X_OFF + SWZ8(c, c * 128 + q * 2)) =
                    f2bf(sim[ct][r] * (1.0f / sm[r]));
            }
    }
    __syncthreads();

    // ---------------- P4: weighted_q = att @ q_h ----------------
    f32x4 wqa[8];
    {
        short8 pa[2];
        const int arow = w * 16 + lr;
        #pragma unroll
        for (int s = 0; s < 2; ++s)
            pa[s] = *(const short8*)(smem + X_OFF + SWZ8(arow, arow * 128 + s * 64 + lg * 16));
        #pragma unroll
        for (int ct = 0; ct < 8; ++ct) {
            f32x4 acc = {0.f, 0.f, 0.f, 0.f};
            const int d = ct * 16 + lr;
            const int dlx = (d << 1) ^ (lg << 5);
            #pragma unroll
            for (int s = 0; s < 2; ++s) {
                const int qbase = (s << 5) + (lg << 3);
                short8 bf;
                #pragma unroll
                for (int j = 0; j < 8; ++j) {
                    // SWZQ(q, q*256 + d*2), q = qbase+j; (q&7)=j, ((q>>3)&3)=lg
                    int off = QH_OFF + ((qbase + j) << 8) + (dlx ^ (j << 4));
                    bf[j] = *(const short*)(smem + off);
                }
                acc = mfma16(pa[s], bf, acc);
            }
            wqa[ct] = acc;
        }
    }
    __syncthreads();   // q_h/att reads done -> wq overwrites QH
    {
        const int cbase = w * 16 + lg * 4;
        #pragma unroll
        for (int ct = 0; ct < 8; ++ct)
            #pragma unroll
            for (int r = 0; r < 4; ++r) {
                int c = cbase + r, d = ct * 16 + lr;
                *(unsigned short*)(smem + QH_OFF + SWZQ(c, c * 256 + d * 2)) =
                    f2bf(wqa[ct][r]);
            }
    }
    __syncthreads();

    // ---------------- P5: column-split GEMM + tanh + W_o -------------------
    {
        f32x4 acc[4][2];
        #pragma unroll
        for (int rt = 0; rt < 4; ++rt) {
            acc[rt][0] = (f32x4){0.f, 0.f, 0.f, 0.f};
            acc[rt][1] = (f32x4){0.f, 0.f, 0.f, 0.f};
        }
        const int n0 = w * 32 + lr, n1 = n0 + 16;
        const int klane = lg * 8;
        short8 qsf[4];
        #pragma unroll
        for (int sk = 0; sk < 4; ++sk)
            qsf[sk] = *(const short8*)(qsum_ws + (b << 7) + sk * 32 + klane);
        const float bh0 = b_h[n0], bh1 = b_h[n1];
        const float wo0 = W_o[n0], wo1 = W_o[n1];

        for (int sk = 0; sk < 4; ++sk) {
            short8 B0[5], B1[5];
            #pragma unroll
            for (int p = 0; p < 5; ++p) {
                B0[p] = *(const short8*)(whT + n0 * 640 + p * 128 + sk * 32 + klane);
                B1[p] = *(const short8*)(whT + n1 * 640 + p * 128 + sk * 32 + klane);
            }
            #pragma unroll
            for (int rt = 0; rt < 4; ++rt) {
                const int row = rt * 16 + lr;
                short8 chf = *(const short8*)(smem + CH_OFF + SWZ8(row, row * 256 + sk * 64 + lg * 16));
                short8 wqf = *(const short8*)(smem + QH_OFF + SWZQ(row, row * 256 + sk * 64 + lg * 16));
                short8 prf, adf;
                #pragma unroll
                for (int e = 0; e < 8; ++e) {
                    float cv = bf2f((unsigned short)chf[e]);
                    float wv = bf2f((unsigned short)wqf[e]);
                    prf[e] = (short)f2bf(cv * wv);
                    adf[e] = (short)f2bf(fabsf(cv - wv));
                }
                acc[rt][0] = mfma16(qsf[sk], B0[0], acc[rt][0]);
                acc[rt][1] = mfma16(qsf[sk], B1[0], acc[rt][1]);
                acc[rt][0] = mfma16(chf,     B0[1], acc[rt][0]);
                acc[rt][1] = mfma16(chf,     B1[1], acc[rt][1]);
                acc[rt][0] = mfma16(wqf,     B0[2], acc[rt][0]);
                acc[rt][1] = mfma16(wqf,     B1[2], acc[rt][1]);
                acc[rt][0] = mfma16(prf,     B0[3], acc[rt][0]);
                acc[rt][1] = mfma16(prf,     B1[3], acc[rt][1]);
                acc[rt][0] = mfma16(adf,     B0[4], acc[rt][0]);
                acc[rt][1] = mfma16(adf,     B1[4], acc[rt][1]);
            }
        }

        #pragma unroll
        for (int rt = 0; rt < 4; ++rt)
            #pragma unroll
            for (int r = 0; r < 4; ++r) {
                float x0 = acc[rt][0][r] + bh0;
                float x1 = acc[rt][1][r] + bh1;
                float t0 = 1.0f - 2.0f / (__expf(2.0f * x0) + 1.0f);  // tanh
                float t1 = 1.0f - 2.0f / (__expf(2.0f * x1) + 1.0f);
                float po = t0 * wo0 + t1 * wo1;
                #pragma unroll
                for (int off = 1; off <= 8; off <<= 1)
                    po += __shfl_xor(po, off);
                if (lr == 0)
                    *(float*)(smem + X_OFF + (w * 64 + rt * 16 + lg * 4 + r) * 4) = po;
            }
    }
    __syncthreads();

    // ---------------- P6: combine wave partials ----------------
    if (tid < 64) {
        float o = b_o[0];
        #pragma unroll
        for (int w2 = 0; w2 < 4; ++w2)
            o += *(const float*)(smem + X_OFF + (w2 * 64 + tid) * 4);
        out[(b << 6) + tid] = o;
    }
}

extern "C" void kernel_launch(void* const* d_in, const int* in_sizes, int n_in,
                              void* d_out, int out_size, void* d_ws, size_t ws_size,
                              hipStream_t stream) {
    const int*   q_ids  = (const int*)d_in[0];
    const int*   c_ids  = (const int*)d_in[1];
    const int*   num_qs = (const int*)d_in[2];
    // d_in[3] num_cols: unused by the reference forward
    const float* embed  = (const float*)d_in[4];
    const float* W_h    = (const float*)d_in[5];
    const float* b_h    = (const float*)d_in[6];
    const float* W_o    = (const float*)d_in[7];
    const float* b_o    = (const float*)d_in[8];
    float*       out    = (float*)d_out;

    // ws: [0,160K) whT | [160K,416K) qsum bf16 [1024][128]
    unsigned short* whT  = (unsigned short*)d_ws;
    unsigned short* qsum = (unsigned short*)((char*)d_ws + 163840);

    el_prep<<<320, 256, 0, stream>>>(W_h, whT);
    el_main<<<1024, 256, 0, stream>>>(q_ids, c_ids, num_qs, embed,
                                      whT, qsum, b_h, W_o, b_o, out);
}